// Round 9
// baseline (270.711 us; speedup 1.0000x reference)
//
#include <hip/hip_runtime.h>
#include <hip/hip_bf16.h>

// Problem constants: B=2, S=2048, D=1024, H=16, HD=64
typedef unsigned short u16;
typedef unsigned int u32;
typedef unsigned long long u64;
typedef _Float16 f16;
typedef __attribute__((__ext_vector_type__(4))) _Float16 f16x4;  // 8B
typedef __attribute__((__ext_vector_type__(8))) short bf16x8;    // 8 bf16 (4 VGPRs)
typedef __attribute__((__ext_vector_type__(4))) float f32x4;     // 16x16 C/D frag
typedef __attribute__((__ext_vector_type__(16))) float f32x16;   // 32x32 C/D frag

__device__ __forceinline__ u16 f2bf(float f) {
    u32 u = __float_as_uint(f);
    return (u16)((u + 0x7fffu + ((u >> 16) & 1u)) >> 16);  // RNE
}

// pack two fp32 -> bf16x2 (truncating; P values only, 3.7x error margin)
__device__ __forceinline__ u32 pk2(float e, float o) {
    return (__float_as_uint(e) >> 16) | (__float_as_uint(o) & 0xFFFF0000u);
}

// ---------------------------------------------------------------------------
// Kernel 1 (fused): blocks 0..8191 = fp32->bf16 cvt of x + weights;
// blocks 8192..40959 = pack M into transposed bitmask
// Mb2[(b*32+w)*2048+q] bit i = (M[b][q][w*64+i] != 0).
// ---------------------------------------------------------------------------
__global__ __launch_bounds__(256) void prep_kernel(
    const float4* __restrict__ x,  const float4* __restrict__ wq,
    const float4* __restrict__ wk, const float4* __restrict__ wv,
    const float4* __restrict__ wo,
    u16* __restrict__ xb, u16* __restrict__ wqb, u16* __restrict__ wkb,
    u16* __restrict__ wvb, u16* __restrict__ wob,
    const int* __restrict__ M, u64* __restrict__ Mb2)
{
    if (blockIdx.x < 8192) {
        int gid = blockIdx.x * 256 + threadIdx.x;        // float4 units
        const float4* src; u16* dst; int off;
        if (gid < 1048576) { src = x; dst = xb; off = gid; }
        else {
            int g = gid - 1048576;
            int sel = g >> 18;
            off = g & 262143;
            src = sel == 0 ? wq : sel == 1 ? wk : sel == 2 ? wv : wo;
            dst = sel == 0 ? wqb : sel == 1 ? wkb : sel == 2 ? wvb : wob;
        }
        float4 f = src[off];
        ushort4 o;
        o.x = f2bf(f.x); o.y = f2bf(f.y); o.z = f2bf(f.z); o.w = f2bf(f.w);
        ((ushort4*)dst)[off] = o;
    } else {
        int wg   = (blockIdx.x - 8192) * 4 + (threadIdx.x >> 6);
        int lane = threadIdx.x & 63;
        int w = wg & 31;
        int q = (wg >> 5) & 2047;
        int b = wg >> 16;
        size_t base = ((size_t)(b * 2048 + q)) * 2048 + w * 64 + lane;
        u64 bits = __ballot(M[base] != 0);
        if (lane == 0) Mb2[(size_t)(b * 32 + w) * 2048 + q] = bits;
    }
}

// ---------------------------------------------------------------------------
// Kernel 2: GEMM C[m,n] = sum_k A[m,k]*B[n,k] (m97 structure, 128xBN, BK=32).
// MODE 0 (BN=128): fused QKV, B = concat(Wq,Wk,Wv).
//   region 0 (n<1024): Q * 0.125*log2(e) -> row-major [token][1024]
//   region 1: K -> frag-swizzled Kfr (S^T A-frag order)
//   region 2: V -> frag-swizzled Vfr (PV  A-frag order)
// Frag layout (u16): ((((b*16+h)*32+kt)*8 + f)*64 + lane)*8 + j
//   Kfr: f=kn*4+t holds K[key=kt*64+kn*32+(lane&31)][d=h*64+t*16+(lane>>5)*8+j]
//   Vfr: f=nd*4+t holds V[key=kt*64+t*16+(lane>>5)*8+j][d=h*64+nd*32+(lane&31)]
// K/V epilogue goes through LDS (two 64-token passes reusing the 16 KB
// staging buffer) so global stores are coalesced b128, not 2B/8B scatter.
// MODE 1 (BN=64): out-projection, fp32 out + bias.
// ---------------------------------------------------------------------------
template<int MODE, int BN>
__global__ __launch_bounds__(256) void gemm_k(
    const u16* __restrict__ Ag, const u16* __restrict__ Bg,
    u16* __restrict__ Cq, u16* __restrict__ Kfr, u16* __restrict__ Vfr,
    float* __restrict__ Cf, const float* __restrict__ bias)
{
    constexpr int Kd = 1024;
    constexpr int NB = BN / 32;
    __shared__ u16 SM[8192];                 // 16 KB: As | Bs, reused by epilogue
    u16* As = SM;                            // 128*32 = 4096 u16
    u16* Bs = SM + 4096;                     // BN*32 u16 (<= 4096)
    const int tid  = threadIdx.x;
    const int wave = tid >> 6, lane = tid & 63;
    const int quad = lane >> 4, l16 = lane & 15;
    const int n0 = blockIdx.x * BN;
    const int m0 = blockIdx.y * 128;

    const int wm = (wave & 1) * 64, wn = (wave >> 1) * (BN / 2);
    f32x4 acc[4][NB];
    #pragma unroll
    for (int i = 0; i < 4; i++)
        #pragma unroll
        for (int j = 0; j < NB; j++)
            acc[i][j] = (f32x4){0.f, 0.f, 0.f, 0.f};

    const int sr = lane >> 2;
    const int sk = (lane & 3) * 8;
    const int ca0 = wave * 2, ca1 = ca0 + 1;
    const u16* gA0 = Ag + (size_t)(m0 + ca0 * 16 + sr) * Kd + sk;
    const u16* gA1 = Ag + (size_t)(m0 + ca1 * 16 + sr) * Kd + sk;
    u16* lA0 = As + ca0 * 512;
    u16* lA1 = As + ca1 * 512;
    const int cb0 = (BN == 128) ? wave * 2 : wave;
    const u16* gB0 = Bg + (size_t)(n0 + cb0 * 16 + sr) * Kd + sk;
    u16* lB0 = Bs + cb0 * 512;
    const u16* gB1 = (BN == 128) ? Bg + (size_t)(n0 + (cb0 + 1) * 16 + sr) * Kd + sk : nullptr;
    u16* lB1 = (BN == 128) ? Bs + (cb0 + 1) * 512 : nullptr;

    #define GLL16(gp, lp) __builtin_amdgcn_global_load_lds( \
        (const __attribute__((address_space(1))) void*)(gp), \
        (__attribute__((address_space(3))) void*)(lp), 16, 0, 0)

    for (int k0 = 0; k0 < Kd; k0 += 32) {
        __syncthreads();
        GLL16(gA0 + k0, lA0);
        GLL16(gA1 + k0, lA1);
        GLL16(gB0 + k0, lB0);
        if (BN == 128) GLL16(gB1 + k0, lB1);
        __syncthreads();

        bf16x8 af[4], bfr[NB];
        #pragma unroll
        for (int mb = 0; mb < 4; mb++)
            af[mb] = *(const bf16x8*)&As[(wm + mb * 16 + l16) * 32 + quad * 8];
        #pragma unroll
        for (int nb = 0; nb < NB; nb++)
            bfr[nb] = *(const bf16x8*)&Bs[(wn + nb * 16 + l16) * 32 + quad * 8];
        #pragma unroll
        for (int mb = 0; mb < 4; mb++)
            #pragma unroll
            for (int nb = 0; nb < NB; nb++)
                acc[mb][nb] = __builtin_amdgcn_mfma_f32_16x16x32_bf16(
                    af[mb], bfr[nb], acc[mb][nb], 0, 0, 0);
    }
    #undef GLL16

    if (MODE == 1) {
        #pragma unroll
        for (int mb = 0; mb < 4; mb++)
            #pragma unroll
            for (int nb = 0; nb < NB; nb++) {
                const int row = m0 + wm + mb * 16 + quad * 4;
                const int col = n0 + wn + nb * 16 + l16;
                #pragma unroll
                for (int r = 0; r < 4; r++)
                    Cf[(size_t)(row + r) * 1024 + col] = acc[mb][nb][r] + bias[col];
            }
        return;
    }

    const int region = n0 >> 10;   // 0:Q 1:K 2:V — uniform per block
    if (region == 0) {
        #pragma unroll
        for (int mb = 0; mb < 4; mb++)
            #pragma unroll
            for (int nb = 0; nb < NB; nb++) {
                const int row = m0 + wm + mb * 16 + quad * 4;
                const int ccol = (n0 & 1023) + wn + nb * 16 + l16;
                #pragma unroll
                for (int r = 0; r < 4; r++)
                    Cq[(size_t)(row + r) * 1024 + ccol] =
                        f2bf(acc[mb][nb][r] * 0.18033688011112042f);
            }
        return;
    }

    // K/V: LDS transpose into frag order, then coalesced b128 global stores.
    // SM pass layout: ((h2*8 + f)*64 + lane)*8 + j  = 8192 u16 (64 tokens).
    const int bb = m0 >> 11;
    const int kt_base = (m0 & 2047) >> 6;
    const int head_base = (n0 & 1023) >> 6;
    u16* dst = (region == 1) ? Kfr : Vfr;
    #pragma unroll
    for (int pass = 0; pass < 2; pass++) {
        __syncthreads();
        #pragma unroll
        for (int mb = 0; mb < 4; mb++) {
            const int rowb = wm + mb * 16 + quad * 4;     // 0..124 within tile
            if ((rowb >> 6) != pass) continue;            // all 4 r share a pass
            #pragma unroll
            for (int nb = 0; nb < NB; nb++) {
                const int ccol = wn + nb * 16 + l16;      // 0..127 within block
                const int h2 = ccol >> 6, dd = ccol & 63;
                if (region == 1) {
                    const int t = dd >> 4, hik = (dd >> 3) & 1, j = dd & 7;
                    #pragma unroll
                    for (int r = 0; r < 4; r++) {
                        const int km = (rowb + r) & 63;
                        const int f = (km >> 5) * 4 + t;
                        const int lanek = hik * 32 + (km & 31);
                        SM[((h2 * 8 + f) * 64 + lanek) * 8 + j] = f2bf(acc[mb][nb][r]);
                    }
                } else {
                    const int kinb = rowb & 63;
                    const int t = kinb >> 4, hiv = (kinb >> 3) & 1, jb = kinb & 7;
                    const int f = (dd >> 5) * 4 + t;
                    const int lanev = hiv * 32 + (dd & 31);
                    ushort4 pk;
                    pk.x = f2bf(acc[mb][nb][0]); pk.y = f2bf(acc[mb][nb][1]);
                    pk.z = f2bf(acc[mb][nb][2]); pk.w = f2bf(acc[mb][nb][3]);
                    *(ushort4*)&SM[((h2 * 8 + f) * 64 + lanev) * 8 + jb] = pk;
                }
            }
        }
        __syncthreads();
        // gather: 256 threads x 32 u16 -> coalesced global b128 stores
        const int h2g = tid >> 7;
        const int inner = (tid & 127) * 32;
        const size_t gbase =
            ((size_t)(bb * 16 + head_base + h2g) * 32 + kt_base + pass) * 4096;
        #pragma unroll
        for (int c = 0; c < 4; c++)
            *(bf16x8*)&dst[gbase + inner + c * 8] =
                *(const bf16x8*)&SM[h2g * 4096 + inner + c * 8];
    }
}

// ---------------------------------------------------------------------------
// Kernel 3: masked attention, S^T formulation, split-K x2, ONE-WAVE blocks.
// blockIdx.x = qt*2 + kh (qt 0..63 -> 32 q-rows; kh = k-tile half).
// Grid (128,16,2) = 4096 blocks = 16 waves/CU grid-side. NO LDS, NO barriers.
// K/V frags from frag-swizzled global (coalesced 1KB loads, L2-hot).
// Two phases per kt (keys 0..31, 32..63) to cap VGPR (4 waves/SIMD).
// Partials: Opart fp16 [kh][bh][q][d], Lpart fp32 [kh][bh][q] -> kernel 4.
// ---------------------------------------------------------------------------
__global__ __launch_bounds__(64) void attn_kernel(
    const u16* __restrict__ Qg, const u16* __restrict__ Kfr, const u16* __restrict__ Vfr,
    const u64* __restrict__ Mb2, f16* __restrict__ Opart, float* __restrict__ Lpart)
{
    const int qt = blockIdx.x >> 1;   // 0..63 (32 q rows per block)
    const int kh = blockIdx.x & 1;    // k-tile half
    const int h  = blockIdx.y;
    const int b  = blockIdx.z;
    const int lane = threadIdx.x;
    const int l31 = lane & 31, hi = lane >> 5;

    const int qrow0 = qt * 32;
    const int bh    = b * 16 + h;

    // Q B-frags (pre-scaled by 0.125*log2e): n=q=l31, k=hi*8+j (+16t)
    bf16x8 qf[4];
    {
        const u16* qp = Qg + ((size_t)b * 2048 + qrow0 + l31) * 1024 + h * 64 + hi * 8;
        #pragma unroll
        for (int t = 0; t < 4; t++) qf[t] = *(const bf16x8*)(qp + t * 16);
    }

    const u16* kfp = Kfr + (size_t)bh * 131072 + lane * 8;   // + (kt*8+f)*512
    const u16* vfp = Vfr + (size_t)bh * 131072 + lane * 8;

    f32x16 oacc0, oacc1;
    #pragma unroll
    for (int i = 0; i < 16; i++) { oacc0[i] = 0.f; oacc1[i] = 0.f; }
    float lsum = 0.f;

    const int kt0 = kh * 16;
    #pragma unroll 1
    for (int kt = kt0; kt < kt0 + 16; kt++) {
        const u64 mwv = Mb2[(size_t)(b * 32 + kt) * 2048 + qrow0 + l31];
        const u32 mlo = ((u32)mwv) >> (hi * 4);
        const u32 mhi = ((u32)(mwv >> 32)) >> (hi * 4);
        const size_t fb = (size_t)(kt * 8) * 512;

        #pragma unroll
        for (int ph = 0; ph < 2; ph++) {
            bf16x8 kf[4], vf[4];
            #pragma unroll
            for (int t = 0; t < 4; t++)
                kf[t] = *(const bf16x8*)(kfp + fb + (size_t)(ph * 4 + t) * 512);
            vf[0] = *(const bf16x8*)(vfp + fb + (size_t)(2 * ph) * 512);
            vf[1] = *(const bf16x8*)(vfp + fb + (size_t)(2 * ph + 1) * 512);
            vf[2] = *(const bf16x8*)(vfp + fb + (size_t)(4 + 2 * ph) * 512);
            vf[3] = *(const bf16x8*)(vfp + fb + (size_t)(4 + 2 * ph + 1) * 512);

            f32x16 s;
            #pragma unroll
            for (int i = 0; i < 16; i++) s[i] = 0.f;
            #pragma unroll
            for (int t = 0; t < 4; t++)
                s = __builtin_amdgcn_mfma_f32_32x32x16_bf16(kf[t], qf[t], s, 0, 0, 0);

            const u32 mm = ph ? mhi : mlo;
            #pragma unroll
            for (int reg = 0; reg < 16; reg++) {
                const int kb2 = (reg & 3) + 8 * (reg >> 2);
                float a = __builtin_amdgcn_exp2f(s[reg]);
                a = ((mm >> kb2) & 1u) ? a : 0.0f;
                s[reg] = a; lsum += a;
            }

            // P^T B-frags for key chunks 32*ph+{0..15,16..31} via lane^32 swap
            bf16x8 pb[2];
            #pragma unroll
            for (int fl = 0; fl < 2; fl++) {
                const int rb = 8 * fl;
                u32 a0 = pk2(s[rb], s[rb + 1]),     a1 = pk2(s[rb + 2], s[rb + 3]);
                u32 a2 = pk2(s[rb + 4], s[rb + 5]), a3 = pk2(s[rb + 6], s[rb + 7]);
                const u32 r0 = __shfl_xor(a0, 32);
                const u32 r1 = __shfl_xor(a1, 32);
                const u32 r2 = __shfl_xor(a2, 32);
                const u32 r3 = __shfl_xor(a3, 32);
                union { u32 u[4]; bf16x8 v; } fu;
                fu.u[0] = hi ? r2 : a0;
                fu.u[1] = hi ? r3 : a1;
                fu.u[2] = hi ? a2 : r0;
                fu.u[3] = hi ? a3 : r1;
                pb[fl] = fu.v;
            }

            // O^T += V^T P^T (this key half)
            oacc0 = __builtin_amdgcn_mfma_f32_32x32x16_bf16(vf[0], pb[0], oacc0, 0, 0, 0);
            oacc0 = __builtin_amdgcn_mfma_f32_32x32x16_bf16(vf[1], pb[1], oacc0, 0, 0, 0);
            oacc1 = __builtin_amdgcn_mfma_f32_32x32x16_bf16(vf[2], pb[0], oacc1, 0, 0, 0);
            oacc1 = __builtin_amdgcn_mfma_f32_32x32x16_bf16(vf[3], pb[1], oacc1, 0, 0, 0);
        }
    }

    lsum += __shfl_xor(lsum, 32);   // combine hi-halves -> row sum for q=l31

    // store partials: Opart[kh][bh][q][d] fp16, Lpart[kh][bh][q]
    const size_t obase = ((size_t)(kh * 32 + bh) * 2048 + qrow0 + l31) * 64;
    #pragma unroll
    for (int tile = 0; tile < 2; tile++) {
        #pragma unroll
        for (int g = 0; g < 4; g++) {
            const int d0 = tile * 32 + g * 8 + hi * 4;
            f16x4 pkv;
            #pragma unroll
            for (int r = 0; r < 4; r++) {
                const int reg = g * 4 + r;
                pkv[r] = (f16)(tile == 0 ? oacc0[reg] : oacc1[reg]);
            }
            *(f16x4*)&Opart[obase + d0] = pkv;
        }
    }
    Lpart[(size_t)kh * 65536 + bh * 2048 + qrow0 + l31] = lsum;
}

// ---------------------------------------------------------------------------
// Kernel 4: merge split-K partials -> AOb[token][h*64+d] bf16.
// ---------------------------------------------------------------------------
__global__ __launch_bounds__(256) void merge_kernel(
    const f16* __restrict__ Opart, const float* __restrict__ Lpart,
    u16* __restrict__ AO)
{
    const int gid = blockIdx.x * 256 + threadIdx.x;   // 0..1048575
    const int c4 = gid & 15;
    const int q  = (gid >> 4) & 2047;
    const int bh = gid >> 15;                         // 0..31
    const int b  = bh >> 4, h = bh & 15;

    const size_t pbase = ((size_t)bh * 2048 + q) * 64 + c4 * 4;
    f16x4 o0 = *(const f16x4*)&Opart[pbase];
    f16x4 o1 = *(const f16x4*)&Opart[(size_t)32 * 2048 * 64 + pbase];
    const float l = Lpart[(size_t)bh * 2048 + q] +
                    Lpart[(size_t)65536 + bh * 2048 + q];
    const float inv = 1.0f / l;

    ushort4 o;
    o.x = f2bf(((float)o0[0] + (float)o1[0]) * inv);
    o.y = f2bf(((float)o0[1] + (float)o1[1]) * inv);
    o.z = f2bf(((float)o0[2] + (float)o1[2]) * inv);
    o.w = f2bf(((float)o0[3] + (float)o1[3]) * inv);
    *(ushort4*)&AO[((size_t)b * 2048 + q) * 1024 + h * 64 + c4 * 4] = o;
}

// ---------------------------------------------------------------------------
extern "C" void kernel_launch(void* const* d_in, const int* in_sizes, int n_in,
                              void* d_out, int out_size, void* d_ws, size_t ws_size,
                              hipStream_t stream)
{
    const float* x  = (const float*)d_in[0];
    const int*   Mm = (const int*)d_in[1];
    const float* Wq = (const float*)d_in[2];
    const float* Wk = (const float*)d_in[3];
    const float* Wv = (const float*)d_in[4];
    const float* Wo = (const float*)d_in[5];
    const float* bo = (const float*)d_in[6];
    float* out = (float*)d_out;

    // workspace layout (u16 elements), ~60 MB total
    u16* ws  = (u16*)d_ws;
    u16* xb  = ws;                 // 4194304
    u16* wqb = xb  + 4194304;      // 1048576 (wq|wk|wv contiguous = 3072x1024)
    u16* wkb = wqb + 1048576;
    u16* wvb = wkb + 1048576;
    u16* wob = wvb + 1048576;
    u16* Qb  = wob + 1048576;      // 4194304 (pre-scaled by 0.125*log2e)
    u16* Kfr = Qb  + 4194304;      // 4194304 frag-swizzled K
    u16* Vfr = Kfr + 4194304;      // 4194304 frag-swizzled V
    u16* AOb = Vfr + 4194304;      // 4194304
    u64* Mb2 = (u64*)(AOb + 4194304);        // 131072 u64 = 1 MB
    f16* Opart = (f16*)(Mb2 + 131072);       // 8388608 f16 = 16.8 MB
    float* Lpart = (float*)(Opart + 8388608);// 131072 f32 = 0.5 MB

    prep_kernel<<<40960, 256, 0, stream>>>(
        (const float4*)x, (const float4*)Wq, (const float4*)Wk,
        (const float4*)Wv, (const float4*)Wo, xb, wqb, wkb, wvb, wob,
        Mm, Mb2);

    dim3 g1(24, 32, 1);  // N=3072/128, M=4096/128 — fused QKV
    gemm_k<0, 128><<<g1, 256, 0, stream>>>(xb, wqb, Qb, Kfr, Vfr, nullptr, nullptr);

    dim3 g2(128, 16, 2); // (qt,kh), H, B — 4096 one-wave blocks
    attn_kernel<<<g2, 64, 0, stream>>>(Qb, Kfr, Vfr, Mb2, Opart, Lpart);

    merge_kernel<<<4096, 256, 0, stream>>>(Opart, Lpart, AOb);

    dim3 g3(16, 32, 1);  // N/64, M/128 — 512 blocks
    gemm_k<1, 64><<<g3, 256, 0, stream>>>(AOb, wob, nullptr, nullptr, nullptr,
                                          out, bo);
}

// Round 10
// 241.686 us; speedup vs baseline: 1.1201x; 1.1201x over previous
//
#include <hip/hip_runtime.h>
#include <hip/hip_bf16.h>

// Problem constants: B=2, S=2048, D=1024, H=16, HD=64
typedef unsigned short u16;
typedef unsigned int u32;
typedef unsigned long long u64;
typedef _Float16 f16;
typedef __attribute__((__ext_vector_type__(4))) _Float16 f16x4;  // 8B
typedef __attribute__((__ext_vector_type__(8))) short bf16x8;    // 8 bf16 (4 VGPRs)
typedef __attribute__((__ext_vector_type__(4))) float f32x4;     // 16x16 C/D frag
typedef __attribute__((__ext_vector_type__(16))) float f32x16;   // 32x32 C/D frag

__device__ __forceinline__ u16 f2bf(float f) {
    u32 u = __float_as_uint(f);
    return (u16)((u + 0x7fffu + ((u >> 16) & 1u)) >> 16);  // RNE
}

// pack two fp32 -> bf16x2 (truncating; P values only, 3.7x error margin)
__device__ __forceinline__ u32 pk2(float e, float o) {
    return (__float_as_uint(e) >> 16) | (__float_as_uint(o) & 0xFFFF0000u);
}

// ---------------------------------------------------------------------------
// Kernel 1 (fused): blocks 0..8191 = fp32->bf16 cvt of x + weights;
// blocks 8192..40959 = pack M into transposed bitmask
// Mb2[(b*32+w)*2048+q] bit i = (M[b][q][w*64+i] != 0).
// ---------------------------------------------------------------------------
__global__ __launch_bounds__(256) void prep_kernel(
    const float4* __restrict__ x,  const float4* __restrict__ wq,
    const float4* __restrict__ wk, const float4* __restrict__ wv,
    const float4* __restrict__ wo,
    u16* __restrict__ xb, u16* __restrict__ wqb, u16* __restrict__ wkb,
    u16* __restrict__ wvb, u16* __restrict__ wob,
    const int* __restrict__ M, u64* __restrict__ Mb2)
{
    if (blockIdx.x < 8192) {
        int gid = blockIdx.x * 256 + threadIdx.x;        // float4 units
        const float4* src; u16* dst; int off;
        if (gid < 1048576) { src = x; dst = xb; off = gid; }
        else {
            int g = gid - 1048576;
            int sel = g >> 18;
            off = g & 262143;
            src = sel == 0 ? wq : sel == 1 ? wk : sel == 2 ? wv : wo;
            dst = sel == 0 ? wqb : sel == 1 ? wkb : sel == 2 ? wvb : wob;
        }
        float4 f = src[off];
        ushort4 o;
        o.x = f2bf(f.x); o.y = f2bf(f.y); o.z = f2bf(f.z); o.w = f2bf(f.w);
        ((ushort4*)dst)[off] = o;
    } else {
        int wg   = (blockIdx.x - 8192) * 4 + (threadIdx.x >> 6);
        int lane = threadIdx.x & 63;
        int w = wg & 31;
        int q = (wg >> 5) & 2047;
        int b = wg >> 16;
        size_t base = ((size_t)(b * 2048 + q)) * 2048 + w * 64 + lane;
        u64 bits = __ballot(M[base] != 0);
        if (lane == 0) Mb2[(size_t)(b * 32 + w) * 2048 + q] = bits;
    }
}

// ---------------------------------------------------------------------------
// Kernel 2: GEMM C[m,n] = sum_k A[m,k]*B[n,k].  128xBN tile, BK=64 as TWO
// independent BK=32 sub-stages (dual-BK32 layout keeps the m97 GLL16 lane
// contiguity and the proven frag addressing while HALVING barrier count).
// MODE 0 (BN=128): fused QKV, B = concat(Wq,Wk,Wv).
//   region 0: Q * 0.125*log2(e) -> row-major [token][1024]
//   region 1: K -> frag-swizzled Kfr (S^T A-frag order)
//   region 2: V -> frag-swizzled Vfr (PV  A-frag order)
// Frag layout (u16): ((((b*16+h)*32+kt)*8 + f)*64 + lane)*8 + j
//   Kfr: f=kn*4+t holds K[key=kt*64+kn*32+(lane&31)][d=h*64+t*16+(lane>>5)*8+j]
//   Vfr: f=nd*4+t holds V[key=kt*64+t*16+(lane>>5)*8+j][d=h*64+nd*32+(lane&31)]
// K/V epilogue via LDS (coalesced b128 global stores).
// MODE 1 (BN=64): out-projection, fp32 out + bias.
// ---------------------------------------------------------------------------
template<int MODE, int BN>
__global__ __launch_bounds__(256) void gemm_k(
    const u16* __restrict__ Ag, const u16* __restrict__ Bg,
    u16* __restrict__ Cq, u16* __restrict__ Kfr, u16* __restrict__ Vfr,
    float* __restrict__ Cf, const float* __restrict__ bias)
{
    constexpr int Kd = 1024;
    constexpr int NB = BN / 32;
    __shared__ u16 SM[8192 + BN * 64];       // As0|As1|Bs0|Bs1
    u16* As0 = SM;                           // 128x32
    u16* As1 = SM + 4096;                    // 128x32 (k-half 1)
    u16* Bs0 = SM + 8192;                    // BNx32
    u16* Bs1 = SM + 8192 + BN * 32;          // BNx32 (k-half 1)
    const int tid  = threadIdx.x;
    const int wave = tid >> 6, lane = tid & 63;
    const int quad = lane >> 4, l16 = lane & 15;
    const int n0 = blockIdx.x * BN;
    const int m0 = blockIdx.y * 128;

    const int wm = (wave & 1) * 64, wn = (wave >> 1) * (BN / 2);
    f32x4 acc[4][NB];
    #pragma unroll
    for (int i = 0; i < 4; i++)
        #pragma unroll
        for (int j = 0; j < NB; j++)
            acc[i][j] = (f32x4){0.f, 0.f, 0.f, 0.f};

    const int sr = lane >> 2;
    const int sk = (lane & 3) * 8;
    const int ca0 = wave * 2, ca1 = ca0 + 1;
    const u16* gA0 = Ag + (size_t)(m0 + ca0 * 16 + sr) * Kd + sk;
    const u16* gA1 = Ag + (size_t)(m0 + ca1 * 16 + sr) * Kd + sk;
    const int cb0 = (BN == 128) ? wave * 2 : wave;
    const u16* gB0 = Bg + (size_t)(n0 + cb0 * 16 + sr) * Kd + sk;
    const u16* gB1 = (BN == 128) ? Bg + (size_t)(n0 + (cb0 + 1) * 16 + sr) * Kd + sk : nullptr;

    #define GLL16(gp, lp) __builtin_amdgcn_global_load_lds( \
        (const __attribute__((address_space(1))) void*)(gp), \
        (__attribute__((address_space(3))) void*)(lp), 16, 0, 0)

    for (int k0 = 0; k0 < Kd; k0 += 64) {
        __syncthreads();
        // k-half 0
        GLL16(gA0 + k0, As0 + ca0 * 512);
        GLL16(gA1 + k0, As0 + ca1 * 512);
        GLL16(gB0 + k0, Bs0 + cb0 * 512);
        if (BN == 128) GLL16(gB1 + k0, Bs0 + (cb0 + 1) * 512);
        // k-half 1
        GLL16(gA0 + k0 + 32, As1 + ca0 * 512);
        GLL16(gA1 + k0 + 32, As1 + ca1 * 512);
        GLL16(gB0 + k0 + 32, Bs1 + cb0 * 512);
        if (BN == 128) GLL16(gB1 + k0 + 32, Bs1 + (cb0 + 1) * 512);
        __syncthreads();

        #pragma unroll
        for (int kk = 0; kk < 2; kk++) {
            const u16* Ah = kk ? As1 : As0;
            const u16* Bh = kk ? Bs1 : Bs0;
            bf16x8 af[4], bfr[NB];
            #pragma unroll
            for (int mb = 0; mb < 4; mb++)
                af[mb] = *(const bf16x8*)&Ah[(wm + mb * 16 + l16) * 32 + quad * 8];
            #pragma unroll
            for (int nb = 0; nb < NB; nb++)
                bfr[nb] = *(const bf16x8*)&Bh[(wn + nb * 16 + l16) * 32 + quad * 8];
            #pragma unroll
            for (int mb = 0; mb < 4; mb++)
                #pragma unroll
                for (int nb = 0; nb < NB; nb++)
                    acc[mb][nb] = __builtin_amdgcn_mfma_f32_16x16x32_bf16(
                        af[mb], bfr[nb], acc[mb][nb], 0, 0, 0);
        }
    }
    #undef GLL16

    if (MODE == 1) {
        #pragma unroll
        for (int mb = 0; mb < 4; mb++)
            #pragma unroll
            for (int nb = 0; nb < NB; nb++) {
                const int row = m0 + wm + mb * 16 + quad * 4;
                const int col = n0 + wn + nb * 16 + l16;
                #pragma unroll
                for (int r = 0; r < 4; r++)
                    Cf[(size_t)(row + r) * 1024 + col] = acc[mb][nb][r] + bias[col];
            }
        return;
    }

    const int region = n0 >> 10;   // 0:Q 1:K 2:V — uniform per block
    if (region == 0) {
        #pragma unroll
        for (int mb = 0; mb < 4; mb++)
            #pragma unroll
            for (int nb = 0; nb < NB; nb++) {
                const int row = m0 + wm + mb * 16 + quad * 4;
                const int ccol = (n0 & 1023) + wn + nb * 16 + l16;
                #pragma unroll
                for (int r = 0; r < 4; r++)
                    Cq[(size_t)(row + r) * 1024 + ccol] =
                        f2bf(acc[mb][nb][r] * 0.18033688011112042f);
            }
        return;
    }

    // K/V: LDS transpose into frag order, then coalesced b128 global stores.
    // SM pass layout: ((h2*8 + f)*64 + lane)*8 + j  = 8192 u16 (64 tokens).
    const int bb = m0 >> 11;
    const int kt_base = (m0 & 2047) >> 6;
    const int head_base = (n0 & 1023) >> 6;
    u16* dst = (region == 1) ? Kfr : Vfr;
    #pragma unroll
    for (int pass = 0; pass < 2; pass++) {
        __syncthreads();
        #pragma unroll
        for (int mb = 0; mb < 4; mb++) {
            const int rowb = wm + mb * 16 + quad * 4;     // 0..124 within tile
            if ((rowb >> 6) != pass) continue;            // all 4 r share a pass
            #pragma unroll
            for (int nb = 0; nb < NB; nb++) {
                const int ccol = wn + nb * 16 + l16;      // 0..127 within block
                const int h2 = ccol >> 6, dd = ccol & 63;
                if (region == 1) {
                    const int t = dd >> 4, hik = (dd >> 3) & 1, j = dd & 7;
                    #pragma unroll
                    for (int r = 0; r < 4; r++) {
                        const int km = (rowb + r) & 63;
                        const int f = (km >> 5) * 4 + t;
                        const int lanek = hik * 32 + (km & 31);
                        SM[((h2 * 8 + f) * 64 + lanek) * 8 + j] = f2bf(acc[mb][nb][r]);
                    }
                } else {
                    const int kinb = rowb & 63;
                    const int t = kinb >> 4, hiv = (kinb >> 3) & 1, jb = kinb & 7;
                    const int f = (dd >> 5) * 4 + t;
                    const int lanev = hiv * 32 + (dd & 31);
                    ushort4 pk;
                    pk.x = f2bf(acc[mb][nb][0]); pk.y = f2bf(acc[mb][nb][1]);
                    pk.z = f2bf(acc[mb][nb][2]); pk.w = f2bf(acc[mb][nb][3]);
                    *(ushort4*)&SM[((h2 * 8 + f) * 64 + lanev) * 8 + jb] = pk;
                }
            }
        }
        __syncthreads();
        const int h2g = tid >> 7;
        const int inner = (tid & 127) * 32;
        const size_t gbase =
            ((size_t)(bb * 16 + head_base + h2g) * 32 + kt_base + pass) * 4096;
        #pragma unroll
        for (int c = 0; c < 4; c++)
            *(bf16x8*)&dst[gbase + inner + c * 8] =
                *(const bf16x8*)&SM[h2g * 4096 + inner + c * 8];
    }
}

// ---------------------------------------------------------------------------
// Kernel 3: masked attention, S^T formulation, split-K x4, 4-wave blocks.
// blockIdx.x = qt*4 + kh (qt 0..15 -> 128 q-rows/block; kh = 8-k-tile slice).
// Grid (64,16,2) = 2048 blocks -> ~28 waves/CU. The block's 4 waves share
// (bh,kh) so their K/V frag streams hit L1 together (R8-verified locality).
// NO LDS, NO barriers, NO cross-wave traffic.
// Partials: Opart fp16 [kh][bh][q][d], Lpart fp32 [kh][bh][q] -> kernel 4.
// ---------------------------------------------------------------------------
__global__ __launch_bounds__(256) void attn_kernel(
    const u16* __restrict__ Qg, const u16* __restrict__ Kfr, const u16* __restrict__ Vfr,
    const u64* __restrict__ Mb2, f16* __restrict__ Opart, float* __restrict__ Lpart)
{
    const int qt = blockIdx.x >> 2;   // 0..15 (128 q rows per block)
    const int kh = blockIdx.x & 3;    // k-tile quarter
    const int h  = blockIdx.y;
    const int b  = blockIdx.z;
    const int tid = threadIdx.x, wave = tid >> 6, lane = tid & 63;
    const int l31 = lane & 31, hi = lane >> 5;

    const int qrow0 = qt * 128 + wave * 32;
    const int bh    = b * 16 + h;

    // Q B-frags (pre-scaled by 0.125*log2e): n=q=l31, k=hi*8+j (+16t)
    bf16x8 qf[4];
    {
        const u16* qp = Qg + ((size_t)b * 2048 + qrow0 + l31) * 1024 + h * 64 + hi * 8;
        #pragma unroll
        for (int t = 0; t < 4; t++) qf[t] = *(const bf16x8*)(qp + t * 16);
    }

    const u16* kfp = Kfr + (size_t)bh * 131072 + lane * 8;   // + (kt*8+f)*512
    const u16* vfp = Vfr + (size_t)bh * 131072 + lane * 8;

    f32x16 oacc0, oacc1;
    #pragma unroll
    for (int i = 0; i < 16; i++) { oacc0[i] = 0.f; oacc1[i] = 0.f; }
    float lsum = 0.f;

    const int kt0 = kh * 8;
    #pragma unroll 1
    for (int kt = kt0; kt < kt0 + 8; kt++) {
        const u64 mwv = Mb2[(size_t)(b * 32 + kt) * 2048 + qrow0 + l31];
        const u32 mlo = ((u32)mwv) >> (hi * 4);
        const u32 mhi = ((u32)(mwv >> 32)) >> (hi * 4);
        const size_t fb = (size_t)(kt * 8) * 512;

        #pragma unroll
        for (int ph = 0; ph < 2; ph++) {
            bf16x8 kf[4], vf[4];
            #pragma unroll
            for (int t = 0; t < 4; t++)
                kf[t] = *(const bf16x8*)(kfp + fb + (size_t)(ph * 4 + t) * 512);
            vf[0] = *(const bf16x8*)(vfp + fb + (size_t)(2 * ph) * 512);
            vf[1] = *(const bf16x8*)(vfp + fb + (size_t)(2 * ph + 1) * 512);
            vf[2] = *(const bf16x8*)(vfp + fb + (size_t)(4 + 2 * ph) * 512);
            vf[3] = *(const bf16x8*)(vfp + fb + (size_t)(4 + 2 * ph + 1) * 512);

            f32x16 s;
            #pragma unroll
            for (int i = 0; i < 16; i++) s[i] = 0.f;
            #pragma unroll
            for (int t = 0; t < 4; t++)
                s = __builtin_amdgcn_mfma_f32_32x32x16_bf16(kf[t], qf[t], s, 0, 0, 0);

            const u32 mm = ph ? mhi : mlo;
            #pragma unroll
            for (int reg = 0; reg < 16; reg++) {
                const int kb2 = (reg & 3) + 8 * (reg >> 2);
                float a = __builtin_amdgcn_exp2f(s[reg]);
                a = ((mm >> kb2) & 1u) ? a : 0.0f;
                s[reg] = a; lsum += a;
            }

            // P^T B-frags for key chunks 32*ph+{0..15,16..31} via lane^32 swap
            bf16x8 pb[2];
            #pragma unroll
            for (int fl = 0; fl < 2; fl++) {
                const int rb = 8 * fl;
                u32 a0 = pk2(s[rb], s[rb + 1]),     a1 = pk2(s[rb + 2], s[rb + 3]);
                u32 a2 = pk2(s[rb + 4], s[rb + 5]), a3 = pk2(s[rb + 6], s[rb + 7]);
                const u32 r0 = __shfl_xor(a0, 32);
                const u32 r1 = __shfl_xor(a1, 32);
                const u32 r2 = __shfl_xor(a2, 32);
                const u32 r3 = __shfl_xor(a3, 32);
                union { u32 u[4]; bf16x8 v; } fu;
                fu.u[0] = hi ? r2 : a0;
                fu.u[1] = hi ? r3 : a1;
                fu.u[2] = hi ? a2 : r0;
                fu.u[3] = hi ? a3 : r1;
                pb[fl] = fu.v;
            }

            // O^T += V^T P^T (this key half)
            oacc0 = __builtin_amdgcn_mfma_f32_32x32x16_bf16(vf[0], pb[0], oacc0, 0, 0, 0);
            oacc0 = __builtin_amdgcn_mfma_f32_32x32x16_bf16(vf[1], pb[1], oacc0, 0, 0, 0);
            oacc1 = __builtin_amdgcn_mfma_f32_32x32x16_bf16(vf[2], pb[0], oacc1, 0, 0, 0);
            oacc1 = __builtin_amdgcn_mfma_f32_32x32x16_bf16(vf[3], pb[1], oacc1, 0, 0, 0);
        }
    }

    lsum += __shfl_xor(lsum, 32);   // combine hi-halves -> row sum for q=l31

    // store partials: Opart[kh][bh][q][d] fp16, Lpart[kh][bh][q]
    const size_t obase = ((size_t)(kh * 32 + bh) * 2048 + qrow0 + l31) * 64;
    #pragma unroll
    for (int tile = 0; tile < 2; tile++) {
        #pragma unroll
        for (int g = 0; g < 4; g++) {
            const int d0 = tile * 32 + g * 8 + hi * 4;
            f16x4 pkv;
            #pragma unroll
            for (int r = 0; r < 4; r++) {
                const int reg = g * 4 + r;
                pkv[r] = (f16)(tile == 0 ? oacc0[reg] : oacc1[reg]);
            }
            *(f16x4*)&Opart[obase + d0] = pkv;
        }
    }
    Lpart[(size_t)kh * 65536 + bh * 2048 + qrow0 + l31] = lsum;
}

// ---------------------------------------------------------------------------
// Kernel 4: merge 4 split-K partials -> AOb[token][h*64+d] bf16.
// ---------------------------------------------------------------------------
__global__ __launch_bounds__(256) void merge_kernel(
    const f16* __restrict__ Opart, const float* __restrict__ Lpart,
    u16* __restrict__ AO)
{
    const int gid = blockIdx.x * 256 + threadIdx.x;   // 0..1048575
    const int c4 = gid & 15;
    const int q  = (gid >> 4) & 2047;
    const int bh = gid >> 15;                         // 0..31
    const int b  = bh >> 4, h = bh & 15;

    float l = 0.f;
    float s0 = 0.f, s1 = 0.f, s2 = 0.f, s3 = 0.f;
    #pragma unroll
    for (int k = 0; k < 4; k++) {
        const size_t pbase = ((size_t)(k * 32 + bh) * 2048 + q) * 64 + c4 * 4;
        f16x4 o = *(const f16x4*)&Opart[pbase];
        s0 += (float)o[0]; s1 += (float)o[1]; s2 += (float)o[2]; s3 += (float)o[3];
        l += Lpart[(size_t)k * 65536 + bh * 2048 + q];
    }
    const float inv = 1.0f / l;
    ushort4 o;
    o.x = f2bf(s0 * inv); o.y = f2bf(s1 * inv);
    o.z = f2bf(s2 * inv); o.w = f2bf(s3 * inv);
    *(ushort4*)&AO[((size_t)b * 2048 + q) * 1024 + h * 64 + c4 * 4] = o;
}

// ---------------------------------------------------------------------------
extern "C" void kernel_launch(void* const* d_in, const int* in_sizes, int n_in,
                              void* d_out, int out_size, void* d_ws, size_t ws_size,
                              hipStream_t stream)
{
    const float* x  = (const float*)d_in[0];
    const int*   Mm = (const int*)d_in[1];
    const float* Wq = (const float*)d_in[2];
    const float* Wk = (const float*)d_in[3];
    const float* Wv = (const float*)d_in[4];
    const float* Wo = (const float*)d_in[5];
    const float* bo = (const float*)d_in[6];
    float* out = (float*)d_out;

    // workspace layout (u16 elements), ~86 MB total
    u16* ws  = (u16*)d_ws;
    u16* xb  = ws;                 // 4194304
    u16* wqb = xb  + 4194304;      // 1048576 (wq|wk|wv contiguous = 3072x1024)
    u16* wkb = wqb + 1048576;
    u16* wvb = wkb + 1048576;
    u16* wob = wvb + 1048576;
    u16* Qb  = wob + 1048576;      // 4194304 (pre-scaled by 0.125*log2e)
    u16* Kfr = Qb  + 4194304;      // 4194304 frag-swizzled K
    u16* Vfr = Kfr + 4194304;      // 4194304 frag-swizzled V
    u16* AOb = Vfr + 4194304;      // 4194304
    u64* Mb2 = (u64*)(AOb + 4194304);          // 131072 u64 = 1 MB
    f16* Opart = (f16*)(Mb2 + 131072);         // 4*32*2048*64 f16 = 33.5 MB
    float* Lpart = (float*)(Opart + 16777216); // 4*65536 f32 = 1 MB

    prep_kernel<<<40960, 256, 0, stream>>>(
        (const float4*)x, (const float4*)Wq, (const float4*)Wk,
        (const float4*)Wv, (const float4*)Wo, xb, wqb, wkb, wvb, wob,
        Mm, Mb2);

    dim3 g1(24, 32, 1);  // N=3072/128, M=4096/128 — fused QKV
    gemm_k<0, 128><<<g1, 256, 0, stream>>>(xb, wqb, Qb, Kfr, Vfr, nullptr, nullptr);

    dim3 g2(64, 16, 2);  // (qt*4+kh), H, B — 2048 four-wave blocks
    attn_kernel<<<g2, 256, 0, stream>>>(Qb, Kfr, Vfr, Mb2, Opart, Lpart);

    merge_kernel<<<4096, 256, 0, stream>>>(Opart, Lpart, AOb);

    dim3 g3(16, 32, 1);  // N/64, M/128 — 512 blocks
    gemm_k<1, 64><<<g3, 256, 0, stream>>>(AOb, wob, nullptr, nullptr, nullptr,
                                          out, bo);
}